// Round 11
// baseline (213.223 us; speedup 1.0000x reference)
//
#include <hip/hip_runtime.h>
#include <hip/hip_bf16.h>

#define B_ 4
#define N_ 4096
#define D_ 128
#define EPB (N_ * D_)        // BYTES per batch in packed fp8 layout = 524288
#define COFF 1024.0f         // colmin positivity offset
#define NBLK (16 * 16 * B_)  // chamfer grid size = 1024

typedef float f32x4 __attribute__((ext_vector_type(4)));
typedef int   int8v __attribute__((ext_vector_type(8)));
typedef int   int4v __attribute__((ext_vector_type(4)));

#define SQRT2 1.41421356237309515f

// ---------------------------------------------------------------------------
// Packed K-major fp8 layout (per batch, BYTE addresses):
//   elem(row, k) -> (row>>4)*2048 + (k>>5)*512 + (row&15)*32 + (k&31)
// K=128 MFMA fragment (16x16x128 f8f6f4): lane (quad,l16): row = l16,
// k = quad*32 + j  ->  32 CONTIGUOUS bytes at rg*2048 + quad*512 + l16*32.
// Register order (k monotone in reg index) verified on HW in R9/R10 (absmax 0).
// ---------------------------------------------------------------------------

// Kernel 1: fp32 -> fp8 e4m3 (*sqrt2) into packed layout + row norms + min
// init + chamfer-completion counter zero. Thread t: row r = t>>4 (in group),
// k-chunk c = t&15 -> consecutive lanes read consecutive 32 B (coalesced).
__global__ __launch_bounds__(256) void prep_kernel(
    const float* __restrict__ X, const float* __restrict__ Y,
    unsigned char* __restrict__ Xb, unsigned char* __restrict__ Yb,
    float* __restrict__ x2, float* __restrict__ y2,
    int* __restrict__ rowmin, int* __restrict__ colmin,
    int* __restrict__ counter)
{
    const int which = blockIdx.y;
    const float* __restrict__ src = which ? Y : X;
    unsigned char* __restrict__ dst = which ? Yb : Xb;
    float* __restrict__ nrm = which ? y2 : x2;
    int* __restrict__ mn = which ? colmin : rowmin;

    const int t = threadIdx.x;
    const int r = t >> 4, c = t & 15;          // r,c in 0..15
    const int rgG = blockIdx.x;                // global row-group
    const int row = rgG * 16 + r;

    if (which == 0 && rgG == 0 && t == 0) *counter = 0;

    const float4 v0 = *(const float4*)(src + (size_t)row * D_ + c * 8);
    const float4 v1 = *(const float4*)(src + (size_t)row * D_ + c * 8 + 4);

    float sq = v0.x * v0.x;
    sq = fmaf(v0.y, v0.y, sq); sq = fmaf(v0.z, v0.z, sq); sq = fmaf(v0.w, v0.w, sq);
    sq = fmaf(v1.x, v1.x, sq); sq = fmaf(v1.y, v1.y, sq);
    sq = fmaf(v1.z, v1.z, sq); sq = fmaf(v1.w, v1.w, sq);
    // reduce across the 16 lanes of this row (xor masks stay in-group)
    #pragma unroll
    for (int m = 1; m < 16; m <<= 1) sq += __shfl_xor(sq, m);

    unsigned lo = 0, hi = 0;
    lo = __builtin_amdgcn_cvt_pk_fp8_f32(v0.x * SQRT2, v0.y * SQRT2, lo, false);
    lo = __builtin_amdgcn_cvt_pk_fp8_f32(v0.z * SQRT2, v0.w * SQRT2, lo, true);
    hi = __builtin_amdgcn_cvt_pk_fp8_f32(v1.x * SQRT2, v1.y * SQRT2, hi, false);
    hi = __builtin_amdgcn_cvt_pk_fp8_f32(v1.z * SQRT2, v1.w * SQRT2, hi, true);

    const int b = row >> 12;
    const int rg = (row & (N_ - 1)) >> 4;
    uint2 packed; packed.x = lo; packed.y = hi;
    // k = c*8:  (k>>5) = c>>2,  (k&31) = (c&3)*8
    *(uint2*)(dst + (size_t)b * EPB + rg * 2048 + (c >> 2) * 512
              + r * 32 + (c & 3) * 8) = packed;

    if (c == 0) {
        nrm[row] = sq;
        mn[row] = 0x7f7fffff;   // +FLT_MAX bits
    }
}

// ---------------------------------------------------------------------------
// Kernel 2: stripe-sweep MX-fp8 (K=128) MFMA chamfer + fused last-block
// finalize. NO LDS staging, NO barriers in the sweep, register-only frags.
// Block = 4 waves x 64 distinct rows = 256-row stripe (grid y = 16).
// Sweeps 4 steps of 64 cols (jc = 256-col chunk, grid x = 16). B-fragments
// double-buffered across the unrolled step loop so next-step loads hide
// behind the current fold; all 16 y2 values hoisted pre-loop.
//   acc == 2*zz (inputs pre-scaled by sqrt2); P = x2 + y2 - acc.
//   C/D layout: row = quad*4 + reg, col = l16   [m89; shape-determined]
// Completion: threadfence + atomicAdd(counter); block #NBLK-1 reduces
// rowmin/colmin (only ever touched by atomics during this kernel -> no
// stale L1 lines) and writes out[0].
// ---------------------------------------------------------------------------
__global__ __launch_bounds__(256, 2) void chamfer_mfma(
    const unsigned char* __restrict__ Xb, const unsigned char* __restrict__ Yb,
    const float* __restrict__ x2, const float* __restrict__ y2,
    int* __restrict__ rowmin, int* __restrict__ colmin,
    int* __restrict__ counter, float* __restrict__ out)
{
    const int b = blockIdx.z;
    const int iT = blockIdx.y;           // 0..15  (256-row stripe)
    const int jc = blockIdx.x;           // 0..15  (256-col chunk)
    const int tid = threadIdx.x;
    const int wave = tid >> 6, lane = tid & 63;
    const int quad = lane >> 4, l16 = lane & 15;
    const int rowBase = iT * 256 + wave * 64;

    const unsigned char* __restrict__ Xp = Xb + (size_t)b * EPB;
    const unsigned char* __restrict__ Yp = Yb + (size_t)b * EPB;

    // ---- A fragments resident (4 x v8i32 = 32 VGPR), register-only build ----
    int8v af[4];
    #pragma unroll
    for (int rt = 0; rt < 4; rt++) {
        const unsigned char* ap = Xp + ((rowBase >> 4) + rt) * 2048
                                 + quad * 512 + l16 * 32;
        const int4v lo = *(const int4v*)(ap);
        const int4v hi = *(const int4v*)(ap + 16);
        af[rt] = (int8v){lo.x, lo.y, lo.z, lo.w, hi.x, hi.y, hi.z, hi.w};
    }
    float x2v[4][4];   // row = rowBase + rt*16 + quad*4 + i
    #pragma unroll
    for (int rt = 0; rt < 4; rt++)
        #pragma unroll
        for (int i = 0; i < 4; i++)
            x2v[rt][i] = x2[(size_t)b * N_ + rowBase + rt * 16 + quad * 4 + i];

    // all 16 y2 values for the sweep (idx = s*4 + ct)
    float y2all[16];
    #pragma unroll
    for (int idx = 0; idx < 16; idx++)
        y2all[idx] = y2[(size_t)b * N_ + jc * 256 + idx * 16 + l16];

    float rmin[4][4];
    #pragma unroll
    for (int rt = 0; rt < 4; rt++)
        #pragma unroll
        for (int i = 0; i < 4; i++) rmin[rt][i] = 3.0e38f;

    // B-fragment double buffer
    int8v bfv[2][4];
    #pragma unroll
    for (int ct = 0; ct < 4; ct++) {
        const unsigned char* bp = Yp + (size_t)((jc * 256) >> 4 << 11)
                                 + ct * 2048 + quad * 512 + l16 * 32;
        const int4v lo = *(const int4v*)(bp);
        const int4v hi = *(const int4v*)(bp + 16);
        bfv[0][ct] = (int8v){lo.x, lo.y, lo.z, lo.w, hi.x, hi.y, hi.z, hi.w};
    }

    #pragma unroll
    for (int s = 0; s < 4; ++s) {
        const int cur = s & 1;
        const int colBase = jc * 256 + s * 64;

        // prefetch next step's B-fragments (hidden behind this step's fold)
        if (s < 3) {
            const int cgn = (jc * 256 + (s + 1) * 64) >> 4;
            #pragma unroll
            for (int ct = 0; ct < 4; ct++) {
                const unsigned char* bp = Yp + (size_t)(cgn + ct) * 2048
                                         + quad * 512 + l16 * 32;
                const int4v lo = *(const int4v*)(bp);
                const int4v hi = *(const int4v*)(bp + 16);
                bfv[cur ^ 1][ct] = (int8v){lo.x, lo.y, lo.z, lo.w,
                                           hi.x, hi.y, hi.z, hi.w};
            }
        }

        f32x4 acc[4][4];
        #pragma unroll
        for (int i = 0; i < 4; i++)
            #pragma unroll
            for (int j = 0; j < 4; j++)
                acc[i][j] = (f32x4){0.f, 0.f, 0.f, 0.f};

        #pragma unroll
        for (int rt = 0; rt < 4; rt++)
            #pragma unroll
            for (int ct = 0; ct < 4; ct++)
                acc[rt][ct] = __builtin_amdgcn_mfma_scale_f32_16x16x128_f8f6f4(
                    af[rt], bfv[cur][ct], acc[rt][ct],
                    0, 0,          // cbsz = fp8 e4m3 (A), blgp = fp8 e4m3 (B)
                    0, 127,        // scale A: e8m0 127 = 1.0
                    0, 127);       // scale B: e8m0 127 = 1.0

        // ---- fold: rmin over cols (persist); cmin over rows (emit now) ----
        float cmin[4];
        #pragma unroll
        for (int ct = 0; ct < 4; ct++) cmin[ct] = 3.0e38f;
        #pragma unroll
        for (int rt = 0; rt < 4; rt++)
            #pragma unroll
            for (int i = 0; i < 4; i++) {
                const float xv = x2v[rt][i];
                float rm = rmin[rt][i];
                #pragma unroll
                for (int ct = 0; ct < 4; ct++) {
                    const float a = acc[rt][ct][i];
                    rm = fminf(rm, y2all[s * 4 + ct] - a);
                    cmin[ct] = fminf(cmin[ct], xv - a);
                }
                rmin[rt][i] = rm;
            }
        #pragma unroll
        for (int ct = 0; ct < 4; ct++) {
            float v = cmin[ct];
            v = fminf(v, __shfl_xor(v, 16));
            v = fminf(v, __shfl_xor(v, 32));
            if (quad == 0)
                atomicMin(&colmin[(size_t)b * N_ + colBase + ct * 16 + l16],
                          __float_as_int(v + COFF));
        }
    }

    // ---- rowmin emission (once per block) ----
    #pragma unroll
    for (int rt = 0; rt < 4; rt++)
        #pragma unroll
        for (int i = 0; i < 4; i++) {
            float v = rmin[rt][i];
            #pragma unroll
            for (int m = 1; m < 16; m <<= 1) v = fminf(v, __shfl_xor(v, m));
            if (l16 == 0) {
                float c = fminf(fmaxf(x2v[rt][i] + v, 0.0f), 100.0f);
                atomicMin(&rowmin[(size_t)b * N_ + rowBase + rt * 16 + quad * 4 + i],
                          __float_as_int(c));
            }
        }

    // ---- fused finalize: last block to finish reduces everything ----
    __threadfence();                      // release my atomics
    __shared__ int isLast;
    __syncthreads();
    if (tid == 0)
        isLast = (atomicAdd(counter, 1) == NBLK - 1);
    __syncthreads();
    if (!isLast) return;
    __threadfence();                      // acquire others' atomics

    float s = 0.f;
    for (int i = tid; i < B_ * N_ / 4; i += 256) {
        int4 v = ((const int4*)rowmin)[i];
        s += __int_as_float(v.x) + __int_as_float(v.y) +
             __int_as_float(v.z) + __int_as_float(v.w);
        int4 c = ((const int4*)colmin)[i];
        float4 yv = ((const float4*)y2)[i];
        s += fminf(fmaxf(__int_as_float(c.x) - COFF + yv.x, 0.f), 100.f);
        s += fminf(fmaxf(__int_as_float(c.y) - COFF + yv.y, 0.f), 100.f);
        s += fminf(fmaxf(__int_as_float(c.z) - COFF + yv.z, 0.f), 100.f);
        s += fminf(fmaxf(__int_as_float(c.w) - COFF + yv.w, 0.f), 100.f);
    }
    #pragma unroll
    for (int m = 1; m < 64; m <<= 1) s += __shfl_xor(s, m);
    __shared__ float sm[4];
    if ((tid & 63) == 0) sm[tid >> 6] = s;
    __syncthreads();
    if (tid == 0)
        out[0] = (sm[0] + sm[1] + sm[2] + sm[3])
                 / ((float)B_ * (float)N_) / (float)B_;
}

extern "C" void kernel_launch(void* const* d_in, const int* in_sizes, int n_in,
                              void* d_out, int out_size, void* d_ws, size_t ws_size,
                              hipStream_t stream) {
    const float* X = (const float*)d_in[0];   // corr_pred   [B,N,D] fp32
    const float* Y = (const float*)d_in[1];   // corr_target [B,N,D] fp32

    char* ws = (char*)d_ws;
    const size_t f8_bytes = (size_t)B_ * N_ * D_;       // 2 MB each (packed fp8)
    unsigned char* Xb = (unsigned char*)ws;
    unsigned char* Yb = (unsigned char*)(ws + f8_bytes);
    char* ws2 = ws + 2 * f8_bytes;
    const size_t vec_bytes = (size_t)B_ * N_ * 4;       // 64 KB each
    float* x2      = (float*)(ws2);
    float* y2      = (float*)(ws2 + vec_bytes);
    int*   rowmin  = (int*)  (ws2 + 2 * vec_bytes);
    int*   colmin  = (int*)  (ws2 + 3 * vec_bytes);
    int*   counter = (int*)  (ws2 + 4 * vec_bytes);
    float* out = (float*)d_out;

    prep_kernel<<<dim3(B_ * N_ / 16, 2), 256, 0, stream>>>(
        X, Y, Xb, Yb, x2, y2, rowmin, colmin, counter);
    chamfer_mfma<<<dim3(16, N_ / 256, B_), 256, 0, stream>>>(
        Xb, Yb, x2, y2, rowmin, colmin, counter, out);
}

// Round 12
// 91.148 us; speedup vs baseline: 2.3393x; 2.3393x over previous
//
#include <hip/hip_runtime.h>
#include <hip/hip_bf16.h>

#define B_ 4
#define N_ 4096
#define D_ 128
#define EPB (N_ * D_)        // BYTES per batch in packed fp8 layout = 524288
#define COFF 1024.0f         // colmin positivity offset

typedef float f32x4 __attribute__((ext_vector_type(4)));
typedef int   int8v __attribute__((ext_vector_type(8)));
typedef int   int4v __attribute__((ext_vector_type(4)));

#define SQRT2 1.41421356237309515f

// ---------------------------------------------------------------------------
// Packed K-major fp8 layout (per batch, BYTE addresses):
//   elem(row, k) -> (row>>4)*2048 + (k>>5)*512 + (row&15)*32 + (k&31)
// K=128 MFMA fragment (16x16x128 f8f6f4): lane (quad,l16): row = l16,
// k = quad*32 + j  ->  32 CONTIGUOUS bytes at rg*2048 + quad*512 + l16*32.
// Register order (k monotone in reg index) verified on HW (R9/R10, absmax 0).
// NOTE (R5/R9/R11 lesson): this kernel lives at the register cliff. No extra
// live arrays, no address-taken vectors, no fused tails — each attempt
// spilled (WRITE_SIZE ~90MB signature) and regressed 3-10x.
// ---------------------------------------------------------------------------

// Kernel 1: fp32 -> fp8 e4m3 (*sqrt2) into packed layout + row norms + min
// init. Thread t: row r = t>>4 (in group), k-chunk c = t&15 -> consecutive
// lanes read consecutive 32 B (fully coalesced). Norm: 4 in-group shuffles.
__global__ __launch_bounds__(256) void prep_kernel(
    const float* __restrict__ X, const float* __restrict__ Y,
    unsigned char* __restrict__ Xb, unsigned char* __restrict__ Yb,
    float* __restrict__ x2, float* __restrict__ y2,
    int* __restrict__ rowmin, int* __restrict__ colmin)
{
    const int which = blockIdx.y;
    const float* __restrict__ src = which ? Y : X;
    unsigned char* __restrict__ dst = which ? Yb : Xb;
    float* __restrict__ nrm = which ? y2 : x2;
    int* __restrict__ mn = which ? colmin : rowmin;

    const int t = threadIdx.x;
    const int r = t >> 4, c = t & 15;          // r,c in 0..15
    const int rgG = blockIdx.x;                // global row-group
    const int row = rgG * 16 + r;

    const float4 v0 = *(const float4*)(src + (size_t)row * D_ + c * 8);
    const float4 v1 = *(const float4*)(src + (size_t)row * D_ + c * 8 + 4);

    float sq = v0.x * v0.x;
    sq = fmaf(v0.y, v0.y, sq); sq = fmaf(v0.z, v0.z, sq); sq = fmaf(v0.w, v0.w, sq);
    sq = fmaf(v1.x, v1.x, sq); sq = fmaf(v1.y, v1.y, sq);
    sq = fmaf(v1.z, v1.z, sq); sq = fmaf(v1.w, v1.w, sq);
    // reduce across the 16 lanes of this row (xor masks stay in-group)
    #pragma unroll
    for (int m = 1; m < 16; m <<= 1) sq += __shfl_xor(sq, m);

    unsigned lo = 0, hi = 0;
    lo = __builtin_amdgcn_cvt_pk_fp8_f32(v0.x * SQRT2, v0.y * SQRT2, lo, false);
    lo = __builtin_amdgcn_cvt_pk_fp8_f32(v0.z * SQRT2, v0.w * SQRT2, lo, true);
    hi = __builtin_amdgcn_cvt_pk_fp8_f32(v1.x * SQRT2, v1.y * SQRT2, hi, false);
    hi = __builtin_amdgcn_cvt_pk_fp8_f32(v1.z * SQRT2, v1.w * SQRT2, hi, true);

    const int b = row >> 12;
    const int rg = (row & (N_ - 1)) >> 4;
    uint2 packed; packed.x = lo; packed.y = hi;
    // k = c*8:  (k>>5) = c>>2,  (k&31) = (c&3)*8
    *(uint2*)(dst + (size_t)b * EPB + rg * 2048 + (c >> 2) * 512
              + r * 32 + (c & 3) * 8) = packed;

    if (c == 0) {
        nrm[row] = sq;
        mn[row] = 0x7f7fffff;   // +FLT_MAX bits
    }
}

// ---------------------------------------------------------------------------
// Kernel 2 (verbatim R10 structure — measured clean: no spill, absmax 0.0):
// stripe-sweep MX-fp8 (K=128) MFMA chamfer. NO LDS, NO barriers, NO alloca.
// Block = 4 waves x 64 distinct rows = 256-row stripe (grid y = 16).
// Sweeps 4 steps of 64 cols (jc = 256-col chunk, grid x = 16).
// 16 K=128 MFMAs per step, e8m0 scale 127 = x1.0 (== non-scaled fp8).
//   acc == 2*zz (inputs pre-scaled by sqrt2); P = x2 + y2 - acc.
//   C/D layout: row = quad*4 + reg, col = l16   [m89; shape-determined]
// ---------------------------------------------------------------------------
__global__ __launch_bounds__(256, 2) void chamfer_mfma(
    const unsigned char* __restrict__ Xb, const unsigned char* __restrict__ Yb,
    const float* __restrict__ x2, const float* __restrict__ y2,
    int* __restrict__ rowmin, int* __restrict__ colmin)
{
    const int b = blockIdx.z;
    const int iT = blockIdx.y;           // 0..15  (256-row stripe)
    const int jc = blockIdx.x;           // 0..15  (256-col chunk)
    const int tid = threadIdx.x;
    const int wave = tid >> 6, lane = tid & 63;
    const int quad = lane >> 4, l16 = lane & 15;
    const int rowBase = iT * 256 + wave * 64;

    const unsigned char* __restrict__ Xp = Xb + (size_t)b * EPB;
    const unsigned char* __restrict__ Yp = Yb + (size_t)b * EPB;

    // ---- A fragments resident (4 x v8i32 = 32 VGPR), register-only build ----
    int8v af[4];
    #pragma unroll
    for (int rt = 0; rt < 4; rt++) {
        const unsigned char* ap = Xp + ((rowBase >> 4) + rt) * 2048
                                 + quad * 512 + l16 * 32;
        const int4v lo = *(const int4v*)(ap);
        const int4v hi = *(const int4v*)(ap + 16);
        af[rt] = (int8v){lo.x, lo.y, lo.z, lo.w, hi.x, hi.y, hi.z, hi.w};
    }
    float x2v[4][4];   // row = rowBase + rt*16 + quad*4 + i
    #pragma unroll
    for (int rt = 0; rt < 4; rt++)
        #pragma unroll
        for (int i = 0; i < 4; i++)
            x2v[rt][i] = x2[(size_t)b * N_ + rowBase + rt * 16 + quad * 4 + i];

    float rmin[4][4];
    #pragma unroll
    for (int rt = 0; rt < 4; rt++)
        #pragma unroll
        for (int i = 0; i < 4; i++) rmin[rt][i] = 3.0e38f;

    for (int s = 0; s < 4; ++s) {
        const int colBase = jc * 256 + s * 64;
        const int cg = colBase >> 4;               // column row-group index

        float y2v[4];
        #pragma unroll
        for (int ct = 0; ct < 4; ct++)
            y2v[ct] = y2[(size_t)b * N_ + colBase + ct * 16 + l16];

        // all 8 B-fragment loads issued before the MFMA burst; register-only
        int8v bfv[4];
        #pragma unroll
        for (int ct = 0; ct < 4; ct++) {
            const unsigned char* bp = Yp + (size_t)(cg + ct) * 2048
                                     + quad * 512 + l16 * 32;
            const int4v lo = *(const int4v*)(bp);
            const int4v hi = *(const int4v*)(bp + 16);
            bfv[ct] = (int8v){lo.x, lo.y, lo.z, lo.w, hi.x, hi.y, hi.z, hi.w};
        }

        f32x4 acc[4][4];
        #pragma unroll
        for (int i = 0; i < 4; i++)
            #pragma unroll
            for (int j = 0; j < 4; j++)
                acc[i][j] = (f32x4){0.f, 0.f, 0.f, 0.f};

        #pragma unroll
        for (int rt = 0; rt < 4; rt++)
            #pragma unroll
            for (int ct = 0; ct < 4; ct++)
                acc[rt][ct] = __builtin_amdgcn_mfma_scale_f32_16x16x128_f8f6f4(
                    af[rt], bfv[ct], acc[rt][ct],
                    0, 0,          // cbsz = fp8 e4m3 (A), blgp = fp8 e4m3 (B)
                    0, 127,        // scale A: e8m0 127 = 1.0
                    0, 127);       // scale B: e8m0 127 = 1.0

        // ---- fold: rmin over cols (persist); cmin over rows (emit now) ----
        float cmin[4];
        #pragma unroll
        for (int ct = 0; ct < 4; ct++) cmin[ct] = 3.0e38f;
        #pragma unroll
        for (int rt = 0; rt < 4; rt++)
            #pragma unroll
            for (int i = 0; i < 4; i++) {
                const float xv = x2v[rt][i];
                float rm = rmin[rt][i];
                #pragma unroll
                for (int ct = 0; ct < 4; ct++) {
                    const float a = acc[rt][ct][i];
                    rm = fminf(rm, y2v[ct] - a);
                    cmin[ct] = fminf(cmin[ct], xv - a);
                }
                rmin[rt][i] = rm;
            }
        #pragma unroll
        for (int ct = 0; ct < 4; ct++) {
            float v = cmin[ct];
            v = fminf(v, __shfl_xor(v, 16));
            v = fminf(v, __shfl_xor(v, 32));
            if (quad == 0)
                atomicMin(&colmin[(size_t)b * N_ + colBase + ct * 16 + l16],
                          __float_as_int(v + COFF));
        }
    }

    // ---- rowmin emission (once per block) ----
    #pragma unroll
    for (int rt = 0; rt < 4; rt++)
        #pragma unroll
        for (int i = 0; i < 4; i++) {
            float v = rmin[rt][i];
            #pragma unroll
            for (int m = 1; m < 16; m <<= 1) v = fminf(v, __shfl_xor(v, m));
            if (l16 == 0) {
                float c = fminf(fmaxf(x2v[rt][i] + v, 0.0f), 100.0f);
                atomicMin(&rowmin[(size_t)b * N_ + rowBase + rt * 16 + quad * 4 + i],
                          __float_as_int(c));
            }
        }
}

// ---------------------------------------------------------------------------
// Kernel 3: final mean, single 1024-thread block, direct write.
// rowmin holds clamped values; colmin holds (min_i(x2_i - acc) + COFF):
// add y2, subtract COFF, clamp here.
// ---------------------------------------------------------------------------
__global__ __launch_bounds__(1024) void finalize_kernel(
    const int* __restrict__ rowmin, const int* __restrict__ colmin,
    const float* __restrict__ y2, float* __restrict__ out)
{
    float s = 0.f;
    for (int i = threadIdx.x; i < B_ * N_ / 4; i += 1024) {
        int4 v = ((const int4*)rowmin)[i];
        s += __int_as_float(v.x) + __int_as_float(v.y) +
             __int_as_float(v.z) + __int_as_float(v.w);
        int4 c = ((const int4*)colmin)[i];
        float4 yv = ((const float4*)y2)[i];
        s += fminf(fmaxf(__int_as_float(c.x) - COFF + yv.x, 0.f), 100.f);
        s += fminf(fmaxf(__int_as_float(c.y) - COFF + yv.y, 0.f), 100.f);
        s += fminf(fmaxf(__int_as_float(c.z) - COFF + yv.z, 0.f), 100.f);
        s += fminf(fmaxf(__int_as_float(c.w) - COFF + yv.w, 0.f), 100.f);
    }
    #pragma unroll
    for (int m = 1; m < 64; m <<= 1) s += __shfl_xor(s, m);
    __shared__ float sm[16];
    if ((threadIdx.x & 63) == 0) sm[threadIdx.x >> 6] = s;
    __syncthreads();
    if (threadIdx.x == 0) {
        float t = 0.f;
        #pragma unroll
        for (int i = 0; i < 16; i++) t += sm[i];
        out[0] = t / ((float)B_ * (float)N_) / (float)B_;
    }
}

extern "C" void kernel_launch(void* const* d_in, const int* in_sizes, int n_in,
                              void* d_out, int out_size, void* d_ws, size_t ws_size,
                              hipStream_t stream) {
    const float* X = (const float*)d_in[0];   // corr_pred   [B,N,D] fp32
    const float* Y = (const float*)d_in[1];   // corr_target [B,N,D] fp32

    char* ws = (char*)d_ws;
    const size_t f8_bytes = (size_t)B_ * N_ * D_;       // 2 MB each (packed fp8)
    unsigned char* Xb = (unsigned char*)ws;
    unsigned char* Yb = (unsigned char*)(ws + f8_bytes);
    char* ws2 = ws + 2 * f8_bytes;
    const size_t vec_bytes = (size_t)B_ * N_ * 4;       // 64 KB each
    float* x2     = (float*)(ws2);
    float* y2     = (float*)(ws2 + vec_bytes);
    int*   rowmin = (int*)  (ws2 + 2 * vec_bytes);
    int*   colmin = (int*)  (ws2 + 3 * vec_bytes);
    float* out = (float*)d_out;

    prep_kernel<<<dim3(B_ * N_ / 16, 2), 256, 0, stream>>>(
        X, Y, Xb, Yb, x2, y2, rowmin, colmin);
    chamfer_mfma<<<dim3(16, N_ / 256, B_), 256, 0, stream>>>(
        Xb, Yb, x2, y2, rowmin, colmin);
    finalize_kernel<<<1, 1024, 0, stream>>>(rowmin, colmin, y2, out);
}